// Round 7
// baseline (384.751 us; speedup 1.0000x reference)
//
#include <hip/hip_runtime.h>

#define SEQ    4096
#define NB     32
#define NC     16         // chunks per sequence
#define CSTEPS 256        // steps per chunk

// ws layout (floats):
//  dtT [32][64][4096]  @ 0
//  xT  [32][64][4096]  @ 8388608
//  BT  [32][16][4096]  @ 16777216
//  CT  [32][16][4096]  @ 18874368
//  Pp  float2 [32*16*16][64] @ 20971520
//  Hin float  [32*16*16][64] @ 22020096

// row_shl:k (0x100|k): lane i <- lane i+k; invalid lanes contribute old (=0).
template <int CTRL>
__device__ __forceinline__ float dpp_add(float s) {
  return s + __int_as_float(__builtin_amdgcn_update_dpp(
                 0, __float_as_int(s), CTRL, 0xf, 0xf, false));
}

// ---------------- Phase 1: per-row projections + transpose ----------------
__global__ __launch_bounds__(256) void ssm_prep(
    const float* __restrict__ x, const float* __restrict__ Wx,
    const float* __restrict__ bx, const float* __restrict__ Wdt,
    const float* __restrict__ bdt, float* __restrict__ ws) {
  __shared__ float xtile[64 * 65];
  __shared__ float ytile[96 * 65];
  const int tid = threadIdx.x;
  const int w = tid >> 6;
  const int l = tid & 63;
  const int b = blockIdx.x >> 6;
  const int t0 = (blockIdx.x & 63) << 6;

  const int lr = l < 36 ? l : 35;
  float wrow[64];
#pragma unroll
  for (int i = 0; i < 16; ++i) {
    const float4 v = ((const float4*)(Wx + lr * 64))[i];
    wrow[4 * i + 0] = v.x; wrow[4 * i + 1] = v.y;
    wrow[4 * i + 2] = v.z; wrow[4 * i + 3] = v.w;
  }
  const float bxv = bx[lr];
  const float4 wdtv = ((const float4*)Wdt)[l];
  const float bdtv = bdt[l];

  float xiv[16];
#pragma unroll
  for (int i = 0; i < 16; ++i)
    xiv[i] = x[((size_t)b * SEQ + (t0 + (w << 4) + i)) * 64 + l];

#pragma unroll
  for (int i = 0; i < 16; ++i) {
    const int tt = (w << 4) + i;
    const float xi = xiv[i];
    xtile[l * 65 + tt] = xi;
    const int xibits = __float_as_int(xi);
    float acc0 = bxv, acc1 = 0.f;
#pragma unroll
    for (int dj = 0; dj < 64; dj += 2) {
      acc0 = fmaf(wrow[dj],     __int_as_float(__builtin_amdgcn_readlane(xibits, dj)),     acc0);
      acc1 = fmaf(wrow[dj + 1], __int_as_float(__builtin_amdgcn_readlane(xibits, dj + 1)), acc1);
    }
    const float acc = acc0 + acc1;
    const int ab = __float_as_int(acc);
    float dtv = bdtv;
    dtv = fmaf(wdtv.x, __int_as_float(__builtin_amdgcn_readlane(ab, 16)), dtv);
    dtv = fmaf(wdtv.y, __int_as_float(__builtin_amdgcn_readlane(ab, 17)), dtv);
    dtv = fmaf(wdtv.z, __int_as_float(__builtin_amdgcn_readlane(ab, 18)), dtv);
    dtv = fmaf(wdtv.w, __int_as_float(__builtin_amdgcn_readlane(ab, 19)), dtv);
    ytile[l * 65 + tt] = dtv;
    if (l < 16)                 ytile[(64 + l) * 65 + tt] = acc;
    else if (l >= 20 && l < 36) ytile[(60 + l) * 65 + tt] = acc;
  }
  __syncthreads();

  float* dtT = ws;
  float* xT  = ws + 8388608;
  float* BT  = ws + 16777216;
  float* CT  = ws + 18874368;
  for (int R = w; R < 160; R += 4) {
    const float v = (R < 64) ? xtile[R * 65 + l] : ytile[(R - 64) * 65 + l];
    float* dst;
    if (R < 64)       dst = xT  + ((size_t)b * 64 + R) * SEQ;
    else if (R < 128) dst = dtT + ((size_t)b * 64 + (R - 64)) * SEQ;
    else if (R < 144) dst = BT  + ((size_t)b * 16 + (R - 128)) * SEQ;
    else              dst = CT  + ((size_t)b * 16 + (R - 144)) * SEQ;
    dst[t0 + l] = v;
  }
}

// id mapping shared by agg/scan: XCD-swizzled so all (c,dg) of one b share an XCD
__device__ __forceinline__ void decode_id(int j, int& b, int& c, int& dg) {
  const int o = ((j & 7) << 10) + (j >> 3);   // 8192 = 8 * 1024, bijective
  b  = o >> 8;
  c  = (o >> 4) & 15;
  dg = o & 15;
}

// ---------------- Phase 2a: per-chunk aggregates (P = prod dA, p = zsr) ----
__global__ __launch_bounds__(64, 6) void ssm_agg(
    const float* __restrict__ ws, const float* __restrict__ A_log,
    float2* __restrict__ Pp) {
  const int lane = threadIdx.x;
  int b, c, dg;
  decode_id(blockIdx.x, b, c, dg);
  const int d0 = dg << 2;
  const int dd = lane >> 4;
  const int n  = lane & 15;
  const int d  = d0 + dd;

  const float Av = -expf(A_log[d * 16 + n]);

  const int tstart = c * CSTEPS;
  const float* dtp = ws +            ((size_t)b * 64 + d) * SEQ + tstart;
  const float* xp  = ws + 8388608  + ((size_t)b * 64 + d) * SEQ + tstart;
  const float* Bp  = ws + 16777216 + ((size_t)b * 16 + n) * SEQ + tstart;

  float P = 1.f, p = 0.f;
  float4 dtc = *(const float4*)dtp;
  float4 xc  = *(const float4*)xp;
  float4 Bc  = *(const float4*)Bp;
  for (int tb = 0; tb < CSTEPS; tb += 4) {
    float4 dtn = dtc, xn = xc, Bn = Bc;
    if (tb + 4 < CSTEPS) {
      dtn = *(const float4*)(dtp + tb + 4);
      xn  = *(const float4*)(xp  + tb + 4);
      Bn  = *(const float4*)(Bp  + tb + 4);
    }
    const float dta[4] = {dtc.x, dtc.y, dtc.z, dtc.w};
    const float xa[4]  = {xc.x,  xc.y,  xc.z,  xc.w};
    const float Ba[4]  = {Bc.x,  Bc.y,  Bc.z,  Bc.w};
#pragma unroll
    for (int q = 0; q < 4; ++q) {
      const float dA = dta[q] * Av;
      p = fmaf(p, dA, (xa[q] * dta[q]) * Ba[q]);
      P *= dA;
    }
    dtc = dtn; xc = xn; Bc = Bn;
  }
  Pp[(size_t)((b * 16 + dg) * NC + c) * 64 + lane] = make_float2(P, p);
}

// ---------------- Phase 2b: serial carry across chunks ---------------------
__global__ __launch_bounds__(64) void ssm_carry(
    const float2* __restrict__ Pp, float* __restrict__ Hin) {
  const int lane = threadIdx.x;
  const int bg = blockIdx.x;            // b*16+dg
  float H = 0.f;
#pragma unroll
  for (int c = 0; c < NC; ++c) {
    const size_t idx = ((size_t)bg * NC + c) * 64 + lane;
    const float2 pp = Pp[idx];
    Hin[idx] = H;
    H = fmaf(pp.x, H, pp.y);
  }
}

// ---------------- Phase 2c: exact scan per chunk, register-streamed --------
__global__ __launch_bounds__(64, 6) void ssm_scan(
    const float* __restrict__ ws, const float* __restrict__ A_log,
    const float* __restrict__ Dp, const float* __restrict__ Hin,
    float* __restrict__ out, float* __restrict__ hidden) {
  const int lane = threadIdx.x;
  int b, c, dg;
  decode_id(blockIdx.x, b, c, dg);
  const int d0 = dg << 2;
  const int dd = lane >> 4;
  const int n  = lane & 15;
  const int d  = d0 + dd;

  const float Av  = -expf(A_log[d * 16 + n]);
  const float Dpv = Dp[d];

  const int tstart = c * CSTEPS;
  const float* dtp = ws +            ((size_t)b * 64 + d) * SEQ + tstart;
  const float* xp  = ws + 8388608  + ((size_t)b * 64 + d) * SEQ + tstart;
  const float* Bp  = ws + 16777216 + ((size_t)b * 16 + n) * SEQ + tstart;
  const float* Cp  = ws + 18874368 + ((size_t)b * 16 + n) * SEQ + tstart;

  float h = Hin[(size_t)((b * 16 + dg) * NC + c) * 64 + lane];
  float* hidp = hidden + ((size_t)b * SEQ + tstart) * 1024 + d0 * 16 + lane;
  float* outp = out + ((size_t)b * SEQ + tstart) * 64 + d;

  float4 dtc = *(const float4*)dtp;
  float4 xc  = *(const float4*)xp;
  float4 Bc  = *(const float4*)Bp;
  float4 Cc  = *(const float4*)Cp;

  for (int tb = 0; tb < CSTEPS; tb += 4) {
    float4 dtn = dtc, xn = xc, Bn = Bc, Cn = Cc;
    if (tb + 4 < CSTEPS) {
      dtn = *(const float4*)(dtp + tb + 4);
      xn  = *(const float4*)(xp  + tb + 4);
      Bn  = *(const float4*)(Bp  + tb + 4);
      Cn  = *(const float4*)(Cp  + tb + 4);
    }
    const float dta[4] = {dtc.x, dtc.y, dtc.z, dtc.w};
    const float xa[4]  = {xc.x,  xc.y,  xc.z,  xc.w};
    const float Ba[4]  = {Bc.x,  Bc.y,  Bc.z,  Bc.w};
    const float Ca[4]  = {Cc.x,  Cc.y,  Cc.z,  Cc.w};
#pragma unroll
    for (int q = 0; q < 4; ++q) {
      const int tq = tb + q;
      h = fmaf(h, dta[q] * Av, (xa[q] * dta[q]) * Ba[q]);
      h = fminf(fmaxf(h, -1000000.0f), 1000000.0f);
      hidp[(size_t)tq * 1024] = h;
      float s = h * Ca[q];
      s = dpp_add<0x108>(s);   // row_shl:8
      s = dpp_add<0x104>(s);   // row_shl:4
      s = dpp_add<0x102>(s);   // row_shl:2
      s = dpp_add<0x101>(s);   // row_shl:1 -> lane n==0 has row sum
      if (n == 0) outp[(size_t)tq * 64] = fmaf(Dpv, xa[q], s);
    }
    dtc = dtn; xc = xn; Bc = Bn; Cc = Cn;
  }
}

extern "C" void kernel_launch(void* const* d_in, const int* in_sizes, int n_in,
                              void* d_out, int out_size, void* d_ws, size_t ws_size,
                              hipStream_t stream) {
  (void)in_sizes; (void)n_in; (void)out_size; (void)ws_size;
  const float* x     = (const float*)d_in[0];
  const float* Wx    = (const float*)d_in[1];
  const float* bx    = (const float*)d_in[2];
  const float* Wdt   = (const float*)d_in[3];
  const float* bdt   = (const float*)d_in[4];
  const float* A_log = (const float*)d_in[5];
  const float* Dp    = (const float*)d_in[6];
  float* out    = (float*)d_out;
  float* hidden = out + (size_t)NB * SEQ * 64;
  float* ws     = (float*)d_ws;
  float2* Pp    = (float2*)(ws + 20971520);
  float*  HinP  = ws + 22020096;

  ssm_prep<<<dim3(2048), dim3(256), 0, stream>>>(x, Wx, bx, Wdt, bdt, ws);
  ssm_agg<<<dim3(8192), dim3(64), 0, stream>>>(ws, A_log, Pp);
  ssm_carry<<<dim3(512), dim3(64), 0, stream>>>(Pp, HinP);
  ssm_scan<<<dim3(8192), dim3(64), 0, stream>>>(ws, A_log, Dp, HinP, out, hidden);
}

// Round 8
// 276.367 us; speedup vs baseline: 1.3922x; 1.3922x over previous
//
#include <hip/hip_runtime.h>

#define SEQ    4096
#define NB     32
#define NC     128        // chunks per sequence
#define CSTEPS 32         // steps per chunk

// ws layout (floats):
//  dtD [32][4096][64]       @ 0
//  BD  [32][4096][16]       @ 8388608
//  CD  [32][4096][16]       @ 10485760
//  Pp  float2 [32][128][1024] @ 12582912   (cell = d*16+n; carry rewrites .x=Hin)
// total 20971520 floats = 83.9 MB

__device__ __forceinline__ void async_copy16(const float* g, float* l) {
  __builtin_amdgcn_global_load_lds(
      (const __attribute__((address_space(1))) void*)g,
      (__attribute__((address_space(3))) void*)l, 16, 0, 0);
}

// ---------------- Phase 1: projections, t-major stores, no transpose -------
__global__ __launch_bounds__(256) void ssm_prep(
    const float* __restrict__ x, const float* __restrict__ Wx,
    const float* __restrict__ bx, const float* __restrict__ Wdt,
    const float* __restrict__ bdt, float* __restrict__ ws) {
  const int tid = threadIdx.x;
  const int w = tid >> 6;
  const int l = tid & 63;
  const int b = blockIdx.x >> 6;
  const int t0 = (blockIdx.x & 63) << 6;

  const int lr = l < 36 ? l : 35;
  float wrow[64];
#pragma unroll
  for (int i = 0; i < 16; ++i) {
    const float4 v = ((const float4*)(Wx + lr * 64))[i];
    wrow[4 * i + 0] = v.x; wrow[4 * i + 1] = v.y;
    wrow[4 * i + 2] = v.z; wrow[4 * i + 3] = v.w;
  }
  const float bxv = bx[lr];
  const float4 wdtv = ((const float4*)Wdt)[l];
  const float bdtv = bdt[l];

  float xiv[16];
#pragma unroll
  for (int i = 0; i < 16; ++i)
    xiv[i] = x[((size_t)b * SEQ + (t0 + (w << 4) + i)) * 64 + l];

  float* dtD = ws;
  float* BD  = ws + 8388608;
  float* CD  = ws + 10485760;

#pragma unroll
  for (int i = 0; i < 16; ++i) {
    const int t = t0 + (w << 4) + i;
    const int xibits = __float_as_int(xiv[i]);
    float acc0 = bxv, acc1 = 0.f;
#pragma unroll
    for (int dj = 0; dj < 64; dj += 2) {
      acc0 = fmaf(wrow[dj],     __int_as_float(__builtin_amdgcn_readlane(xibits, dj)),     acc0);
      acc1 = fmaf(wrow[dj + 1], __int_as_float(__builtin_amdgcn_readlane(xibits, dj + 1)), acc1);
    }
    const float acc = acc0 + acc1;       // xp[l], valid l<36
    const int ab = __float_as_int(acc);
    float dtv = bdtv;
    dtv = fmaf(wdtv.x, __int_as_float(__builtin_amdgcn_readlane(ab, 16)), dtv);
    dtv = fmaf(wdtv.y, __int_as_float(__builtin_amdgcn_readlane(ab, 17)), dtv);
    dtv = fmaf(wdtv.z, __int_as_float(__builtin_amdgcn_readlane(ab, 18)), dtv);
    dtv = fmaf(wdtv.w, __int_as_float(__builtin_amdgcn_readlane(ab, 19)), dtv);
    dtD[((size_t)b * SEQ + t) * 64 + l] = dtv;
    if (l < 16)                 BD[((size_t)b * SEQ + t) * 16 + l] = acc;
    else if (l >= 20 && l < 36) CD[((size_t)b * SEQ + t) * 16 + (l - 20)] = acc;
  }
}

// ---------------- Phase 2a: per-chunk aggregates, lane = d -----------------
__global__ __launch_bounds__(64, 4) void ssm_agg(
    const float* __restrict__ ws, const float* __restrict__ x,
    const float* __restrict__ A_log, float2* __restrict__ Pp) {
  __shared__ __align__(16) float Bs[512];
  const int lane = threadIdx.x;          // = d
  const int b = blockIdx.x >> 7;
  const int c = blockIdx.x & 127;
  const int t0 = c << 5;

  const float* dtp = ws + ((size_t)b * SEQ + t0) * 64 + lane;
  const float* xpp = x  + ((size_t)b * SEQ + t0) * 64 + lane;
  const float* Bg  = ws + 8388608 + ((size_t)b * SEQ + t0) * 16;

  async_copy16(Bg + lane * 4, Bs);
  async_copy16(Bg + 256 + lane * 4, Bs + 256);

  float dA8[8], xA8[8], dB8[8], xB8[8];
  auto load8 = [&](float (&db)[8], float (&xb)[8], int T) {
#pragma unroll
    for (int j = 0; j < 8; ++j) {
      db[j] = dtp[(size_t)(T + j) * 64];
      xb[j] = xpp[(size_t)(T + j) * 64];
    }
  };
  load8(dA8, xA8, 0);
  load8(dB8, xB8, 8);

  float Av[16];
  {
    const float4* ar = (const float4*)(A_log + lane * 16);
#pragma unroll
    for (int k = 0; k < 4; ++k) {
      const float4 a = ar[k];
      Av[4*k+0] = -expf(a.x); Av[4*k+1] = -expf(a.y);
      Av[4*k+2] = -expf(a.z); Av[4*k+3] = -expf(a.w);
    }
  }

  float P[16], p[16];
#pragma unroll
  for (int n = 0; n < 16; ++n) { P[n] = 1.f; p[n] = 0.f; }

  asm volatile("s_waitcnt vmcnt(0)" ::: "memory");

  auto step = [&](float dtv, float xv, int t) {
    const float xd = xv * dtv;
    const float4* Bq4 = (const float4*)(Bs + t * 16);
#pragma unroll
    for (int k = 0; k < 4; ++k) {
      const float4 Bq = Bq4[k];
      const float Ba[4] = {Bq.x, Bq.y, Bq.z, Bq.w};
#pragma unroll
      for (int u = 0; u < 4; ++u) {
        const int n = 4 * k + u;
        const float dA = dtv * Av[n];
        p[n] = fmaf(p[n], dA, xd * Ba[u]);
        P[n] *= dA;
      }
    }
  };
  auto comp8 = [&](float (&db)[8], float (&xb)[8], int T) {
#pragma unroll
    for (int q = 0; q < 8; ++q) step(db[q], xb[q], T + q);
  };

  comp8(dA8, xA8, 0);  load8(dA8, xA8, 16);
  comp8(dB8, xB8, 8);  load8(dB8, xB8, 24);
  comp8(dA8, xA8, 16);
  comp8(dB8, xB8, 24);

  float4* dst = (float4*)(Pp + (size_t)(b * 128 + c) * 1024 + lane * 16);
#pragma unroll
  for (int jj = 0; jj < 8; ++jj)
    dst[jj] = make_float4(P[2*jj], p[2*jj], P[2*jj+1], p[2*jj+1]);
}

// ---------------- Phase 2b: serial carry; writes Hin into Pp[.].x ----------
__global__ __launch_bounds__(256) void ssm_carry(float2* __restrict__ Pp) {
  const int b = blockIdx.x >> 2;
  const int cell = ((blockIdx.x & 3) << 8) + threadIdx.x;
  float2* base = Pp + (size_t)b * (128 * 1024) + cell;
  float H = 0.f;
#pragma unroll 4
  for (int c = 0; c < 128; ++c) {
    const float2 pp = base[(size_t)c * 1024];
    ((float*)(base + (size_t)c * 1024))[0] = H;
    H = fmaf(pp.x, H, pp.y);
  }
}

// ---------------- Phase 2c: exact scan, lane = d, h[16] in registers -------
__global__ __launch_bounds__(64, 4) void ssm_scan(
    const float* __restrict__ ws, const float* __restrict__ x,
    const float* __restrict__ A_log, const float* __restrict__ Dp,
    float* __restrict__ out, float* __restrict__ hidden) {
  __shared__ __align__(16) float Bs[512];
  __shared__ __align__(16) float Cs[512];
  const int lane = threadIdx.x;          // = d
  const int b = blockIdx.x >> 7;
  const int c = blockIdx.x & 127;
  const int t0 = c << 5;

  const float* dtp = ws + ((size_t)b * SEQ + t0) * 64 + lane;
  const float* xpp = x  + ((size_t)b * SEQ + t0) * 64 + lane;
  const float* Bg  = ws + 8388608  + ((size_t)b * SEQ + t0) * 16;
  const float* Cg  = ws + 10485760 + ((size_t)b * SEQ + t0) * 16;

  async_copy16(Bg + lane * 4, Bs);
  async_copy16(Bg + 256 + lane * 4, Bs + 256);
  async_copy16(Cg + lane * 4, Cs);
  async_copy16(Cg + 256 + lane * 4, Cs + 256);

  float dA8[8], xA8[8], dB8[8], xB8[8];
  auto load8 = [&](float (&db)[8], float (&xb)[8], int T) {
#pragma unroll
    for (int j = 0; j < 8; ++j) {
      db[j] = dtp[(size_t)(T + j) * 64];
      xb[j] = xpp[(size_t)(T + j) * 64];
    }
  };
  load8(dA8, xA8, 0);
  load8(dB8, xB8, 8);

  float Av[16];
  {
    const float4* ar = (const float4*)(A_log + lane * 16);
#pragma unroll
    for (int k = 0; k < 4; ++k) {
      const float4 a = ar[k];
      Av[4*k+0] = -expf(a.x); Av[4*k+1] = -expf(a.y);
      Av[4*k+2] = -expf(a.z); Av[4*k+3] = -expf(a.w);
    }
  }
  const float Dpv = Dp[lane];

  float h[16];
  {
    const float4* pp = (const float4*)(ws + 12582912 +
        ((size_t)(b * 128 + c) * 1024 + lane * 16) * 2);
#pragma unroll
    for (int jj = 0; jj < 8; ++jj) {
      const float4 v = pp[jj];
      h[2*jj] = v.x; h[2*jj+1] = v.z;   // .x = Hin (carry), .z = next cell's Hin
    }
  }

  float* hidp = hidden + (((size_t)b * SEQ + t0) * 64 + lane) * 16;
  float* outp = out + ((size_t)b * SEQ + t0) * 64 + lane;

  asm volatile("s_waitcnt vmcnt(0)" ::: "memory");

  auto step = [&](float dtv, float xv, int t) {
    const float xd = xv * dtv;
    float y = 0.f;
    const float4* Bq4 = (const float4*)(Bs + t * 16);
    const float4* Cq4 = (const float4*)(Cs + t * 16);
#pragma unroll
    for (int k = 0; k < 4; ++k) {
      const float4 Bq = Bq4[k];
      const float4 Cq = Cq4[k];
      const float Ba[4] = {Bq.x, Bq.y, Bq.z, Bq.w};
      const float Ca[4] = {Cq.x, Cq.y, Cq.z, Cq.w};
#pragma unroll
      for (int u = 0; u < 4; ++u) {
        const int n = 4 * k + u;
        float hv = fmaf(h[n], dtv * Av[n], xd * Ba[u]);
        hv = fminf(fmaxf(hv, -1000000.0f), 1000000.0f);
        h[n] = hv;
        y = fmaf(hv, Ca[u], y);
      }
    }
    *(float4*)(hidp + (size_t)t * 1024 +  0) = make_float4(h[0],  h[1],  h[2],  h[3]);
    *(float4*)(hidp + (size_t)t * 1024 +  4) = make_float4(h[4],  h[5],  h[6],  h[7]);
    *(float4*)(hidp + (size_t)t * 1024 +  8) = make_float4(h[8],  h[9],  h[10], h[11]);
    *(float4*)(hidp + (size_t)t * 1024 + 12) = make_float4(h[12], h[13], h[14], h[15]);
    outp[(size_t)t * 64] = fmaf(Dpv, xv, y);
  };
  auto comp8 = [&](float (&db)[8], float (&xb)[8], int T) {
#pragma unroll
    for (int q = 0; q < 8; ++q) step(db[q], xb[q], T + q);
  };

  comp8(dA8, xA8, 0);  load8(dA8, xA8, 16);
  comp8(dB8, xB8, 8);  load8(dB8, xB8, 24);
  comp8(dA8, xA8, 16);
  comp8(dB8, xB8, 24);
}

extern "C" void kernel_launch(void* const* d_in, const int* in_sizes, int n_in,
                              void* d_out, int out_size, void* d_ws, size_t ws_size,
                              hipStream_t stream) {
  (void)in_sizes; (void)n_in; (void)out_size; (void)ws_size;
  const float* x     = (const float*)d_in[0];
  const float* Wx    = (const float*)d_in[1];
  const float* bx    = (const float*)d_in[2];
  const float* Wdt   = (const float*)d_in[3];
  const float* bdt   = (const float*)d_in[4];
  const float* A_log = (const float*)d_in[5];
  const float* Dp    = (const float*)d_in[6];
  float* out    = (float*)d_out;
  float* hidden = out + (size_t)NB * SEQ * 64;
  float* ws     = (float*)d_ws;
  float2* Pp    = (float2*)(ws + 12582912);

  ssm_prep<<<dim3(2048), dim3(256), 0, stream>>>(x, Wx, bx, Wdt, bdt, ws);
  ssm_agg<<<dim3(4096), dim3(64), 0, stream>>>(ws, x, A_log, Pp);
  ssm_carry<<<dim3(128), dim3(256), 0, stream>>>(Pp);
  ssm_scan<<<dim3(4096), dim3(64), 0, stream>>>(ws, x, A_log, Dp, out, hidden);
}

// Round 9
// 264.113 us; speedup vs baseline: 1.4568x; 1.0464x over previous
//
#include <hip/hip_runtime.h>

#define SEQ    4096
#define NB     32
#define NC     128        // chunks per sequence
#define CSTEPS 32         // steps per chunk

// ws layout (floats):
//  dtD [32][4096][64]         @ 0
//  BD  [32][4096][16]         @ 8388608
//  CD  [32][4096][16]         @ 10485760
//  Pp  float2 [32][128][1024] @ 12582912  (cell = d*16+n; carry rewrites .x=Hin)
// total 20971520 floats = 83.9 MB

__device__ __forceinline__ void async_copy16(const float* g, float* l) {
  __builtin_amdgcn_global_load_lds(
      (const __attribute__((address_space(1))) void*)g,
      (__attribute__((address_space(3))) void*)l, 16, 0, 0);
}

// ------------- Phase 1: projections + per-chunk aggregates (fused) ---------
__global__ __launch_bounds__(256, 4) void ssm_prep(
    const float* __restrict__ x, const float* __restrict__ Wx,
    const float* __restrict__ bx, const float* __restrict__ Wdt,
    const float* __restrict__ bdt, const float* __restrict__ A_log,
    float* __restrict__ ws, float2* __restrict__ Pp) {
  __shared__ float dts[64 * 64];   // [t][d]
  __shared__ float xds[64 * 64];   // [t][d] = x*dt
  __shared__ float Bs[64 * 16];    // [t][n]
  const int tid = threadIdx.x;
  const int w = tid >> 6;
  const int l = tid & 63;
  const int b = blockIdx.x >> 6;
  const int t0 = (blockIdx.x & 63) << 6;

  const int lr = l < 36 ? l : 35;
  float wrow[64];
#pragma unroll
  for (int i = 0; i < 16; ++i) {
    const float4 v = ((const float4*)(Wx + lr * 64))[i];
    wrow[4 * i + 0] = v.x; wrow[4 * i + 1] = v.y;
    wrow[4 * i + 2] = v.z; wrow[4 * i + 3] = v.w;
  }
  const float bxv = bx[lr];
  const float4 wdtv = ((const float4*)Wdt)[l];
  const float bdtv = bdt[l];

  float xiv[16];
#pragma unroll
  for (int i = 0; i < 16; ++i)
    xiv[i] = x[((size_t)b * SEQ + (t0 + (w << 4) + i)) * 64 + l];

  float* dtD = ws;
  float* BD  = ws + 8388608;
  float* CD  = ws + 10485760;

#pragma unroll
  for (int i = 0; i < 16; ++i) {
    const int tl = (w << 4) + i;          // local t
    const int t  = t0 + tl;
    const int xibits = __float_as_int(xiv[i]);
    float acc0 = bxv, acc1 = 0.f;
#pragma unroll
    for (int dj = 0; dj < 64; dj += 2) {
      acc0 = fmaf(wrow[dj],     __int_as_float(__builtin_amdgcn_readlane(xibits, dj)),     acc0);
      acc1 = fmaf(wrow[dj + 1], __int_as_float(__builtin_amdgcn_readlane(xibits, dj + 1)), acc1);
    }
    const float acc = acc0 + acc1;       // xp[l], valid l<36
    const int ab = __float_as_int(acc);
    float dtv = bdtv;
    dtv = fmaf(wdtv.x, __int_as_float(__builtin_amdgcn_readlane(ab, 16)), dtv);
    dtv = fmaf(wdtv.y, __int_as_float(__builtin_amdgcn_readlane(ab, 17)), dtv);
    dtv = fmaf(wdtv.z, __int_as_float(__builtin_amdgcn_readlane(ab, 18)), dtv);
    dtv = fmaf(wdtv.w, __int_as_float(__builtin_amdgcn_readlane(ab, 19)), dtv);
    dtD[((size_t)b * SEQ + t) * 64 + l] = dtv;
    dts[tl * 64 + l] = dtv;
    xds[tl * 64 + l] = xiv[i] * dtv;
    if (l < 16) {
      BD[((size_t)b * SEQ + t) * 16 + l] = acc;
      Bs[tl * 16 + l] = acc;
    } else if (l >= 20 && l < 36) {
      CD[((size_t)b * SEQ + t) * 16 + (l - 20)] = acc;
    }
  }
  __syncthreads();

  // Phase B: per-chunk aggregates. thread -> d = tid>>2, n = n0..n0+3
  const int d  = tid >> 2;
  const int n0 = (tid & 3) << 2;
  float Av4[4];
  {
    const float4 a = *(const float4*)(A_log + d * 16 + n0);
    Av4[0] = -expf(a.x); Av4[1] = -expf(a.y);
    Av4[2] = -expf(a.z); Av4[3] = -expf(a.w);
  }
  float2* PpB = Pp + (size_t)b * (128 * 1024);
#pragma unroll
  for (int cl = 0; cl < 2; ++cl) {
    float P0 = 1.f, P1 = 1.f, P2 = 1.f, P3 = 1.f;
    float q0 = 0.f, q1 = 0.f, q2 = 0.f, q3 = 0.f;
#pragma unroll
    for (int s = 0; s < 32; ++s) {
      const int tl = (cl << 5) + s;
      const float dtv = dts[tl * 64 + d];
      const float xdt = xds[tl * 64 + d];
      const float4 Bq = *(const float4*)(&Bs[tl * 16 + n0]);
      float dA;
      dA = dtv * Av4[0]; q0 = fmaf(q0, dA, xdt * Bq.x); P0 *= dA;
      dA = dtv * Av4[1]; q1 = fmaf(q1, dA, xdt * Bq.y); P1 *= dA;
      dA = dtv * Av4[2]; q2 = fmaf(q2, dA, xdt * Bq.z); P2 *= dA;
      dA = dtv * Av4[3]; q3 = fmaf(q3, dA, xdt * Bq.w); P3 *= dA;
    }
    const int c = (t0 >> 5) + cl;
    float4* dst = (float4*)(PpB + (size_t)c * 1024 + d * 16 + n0);
    dst[0] = make_float4(P0, q0, P1, q1);
    dst[1] = make_float4(P2, q2, P3, q3);
  }
}

// ------------- Phase 2: serial carry, batched prefetch; Hin -> Pp[.].x -----
__global__ __launch_bounds__(256) void ssm_carry(float2* __restrict__ Pp) {
  const int b = blockIdx.x >> 2;
  const int cell = ((blockIdx.x & 3) << 8) + threadIdx.x;
  float2* base = Pp + (size_t)b * (128 * 1024) + cell;
  float H = 0.f;
#pragma unroll
  for (int g = 0; g < 8; ++g) {
    float2 v[16];
#pragma unroll
    for (int j = 0; j < 16; ++j) v[j] = base[(size_t)(g * 16 + j) * 1024];
#pragma unroll
    for (int j = 0; j < 16; ++j) {
      base[(size_t)(g * 16 + j) * 1024].x = H;
      H = fmaf(v[j].x, H, v[j].y);
    }
  }
}

// ------------- Phase 3: exact scan, lane = d, h[16] in registers -----------
__global__ __launch_bounds__(64, 4) void ssm_scan(
    const float* __restrict__ ws, const float* __restrict__ x,
    const float* __restrict__ A_log, const float* __restrict__ Dp,
    float* __restrict__ out, float* __restrict__ hidden) {
  __shared__ __align__(16) float Bs[512];
  __shared__ __align__(16) float Cs[512];
  const int lane = threadIdx.x;          // = d
  const int b = blockIdx.x >> 7;
  const int c = blockIdx.x & 127;
  const int t0 = c << 5;

  const float* dtp = ws + ((size_t)b * SEQ + t0) * 64 + lane;
  const float* xpp = x  + ((size_t)b * SEQ + t0) * 64 + lane;
  const float* Bg  = ws + 8388608  + ((size_t)b * SEQ + t0) * 16;
  const float* Cg  = ws + 10485760 + ((size_t)b * SEQ + t0) * 16;

  async_copy16(Bg + lane * 4, Bs);
  async_copy16(Bg + 256 + lane * 4, Bs + 256);
  async_copy16(Cg + lane * 4, Cs);
  async_copy16(Cg + 256 + lane * 4, Cs + 256);

  float dA8[8], xA8[8], dB8[8], xB8[8];
  auto load8 = [&](float (&db)[8], float (&xb)[8], int T) {
#pragma unroll
    for (int j = 0; j < 8; ++j) {
      db[j] = dtp[(size_t)(T + j) * 64];
      xb[j] = xpp[(size_t)(T + j) * 64];
    }
  };
  load8(dA8, xA8, 0);
  load8(dB8, xB8, 8);

  float Av[16];
  {
    const float4* ar = (const float4*)(A_log + lane * 16);
#pragma unroll
    for (int k = 0; k < 4; ++k) {
      const float4 a = ar[k];
      Av[4*k+0] = -expf(a.x); Av[4*k+1] = -expf(a.y);
      Av[4*k+2] = -expf(a.z); Av[4*k+3] = -expf(a.w);
    }
  }
  const float Dpv = Dp[lane];

  float h[16];
  {
    const float4* pp = (const float4*)(ws + 12582912 +
        ((size_t)(b * 128 + c) * 1024 + lane * 16) * 2);
#pragma unroll
    for (int jj = 0; jj < 8; ++jj) {
      const float4 v = pp[jj];
      h[2*jj] = v.x; h[2*jj+1] = v.z;   // .x = Hin written by carry
    }
  }

  float* hidp = hidden + (((size_t)b * SEQ + t0) * 64 + lane) * 16;
  float* outp = out + ((size_t)b * SEQ + t0) * 64 + lane;

  asm volatile("s_waitcnt vmcnt(0)" ::: "memory");

  auto step = [&](float dtv, float xv, int t) {
    const float xd = xv * dtv;
    float y0 = 0.f, y1 = 0.f, y2 = 0.f, y3 = 0.f;
    const float4* Bq4 = (const float4*)(Bs + t * 16);
    const float4* Cq4 = (const float4*)(Cs + t * 16);
    {
      const float4 Bq = Bq4[0], Cq = Cq4[0];
      float hv;
      hv = __builtin_amdgcn_fmed3f(fmaf(h[0], dtv*Av[0], xd*Bq.x), -1e6f, 1e6f); h[0] = hv; y0 = fmaf(hv, Cq.x, y0);
      hv = __builtin_amdgcn_fmed3f(fmaf(h[1], dtv*Av[1], xd*Bq.y), -1e6f, 1e6f); h[1] = hv; y1 = fmaf(hv, Cq.y, y1);
      hv = __builtin_amdgcn_fmed3f(fmaf(h[2], dtv*Av[2], xd*Bq.z), -1e6f, 1e6f); h[2] = hv; y2 = fmaf(hv, Cq.z, y2);
      hv = __builtin_amdgcn_fmed3f(fmaf(h[3], dtv*Av[3], xd*Bq.w), -1e6f, 1e6f); h[3] = hv; y3 = fmaf(hv, Cq.w, y3);
    }
    {
      const float4 Bq = Bq4[1], Cq = Cq4[1];
      float hv;
      hv = __builtin_amdgcn_fmed3f(fmaf(h[4], dtv*Av[4], xd*Bq.x), -1e6f, 1e6f); h[4] = hv; y0 = fmaf(hv, Cq.x, y0);
      hv = __builtin_amdgcn_fmed3f(fmaf(h[5], dtv*Av[5], xd*Bq.y), -1e6f, 1e6f); h[5] = hv; y1 = fmaf(hv, Cq.y, y1);
      hv = __builtin_amdgcn_fmed3f(fmaf(h[6], dtv*Av[6], xd*Bq.z), -1e6f, 1e6f); h[6] = hv; y2 = fmaf(hv, Cq.z, y2);
      hv = __builtin_amdgcn_fmed3f(fmaf(h[7], dtv*Av[7], xd*Bq.w), -1e6f, 1e6f); h[7] = hv; y3 = fmaf(hv, Cq.w, y3);
    }
    {
      const float4 Bq = Bq4[2], Cq = Cq4[2];
      float hv;
      hv = __builtin_amdgcn_fmed3f(fmaf(h[8],  dtv*Av[8],  xd*Bq.x), -1e6f, 1e6f); h[8]  = hv; y0 = fmaf(hv, Cq.x, y0);
      hv = __builtin_amdgcn_fmed3f(fmaf(h[9],  dtv*Av[9],  xd*Bq.y), -1e6f, 1e6f); h[9]  = hv; y1 = fmaf(hv, Cq.y, y1);
      hv = __builtin_amdgcn_fmed3f(fmaf(h[10], dtv*Av[10], xd*Bq.z), -1e6f, 1e6f); h[10] = hv; y2 = fmaf(hv, Cq.z, y2);
      hv = __builtin_amdgcn_fmed3f(fmaf(h[11], dtv*Av[11], xd*Bq.w), -1e6f, 1e6f); h[11] = hv; y3 = fmaf(hv, Cq.w, y3);
    }
    {
      const float4 Bq = Bq4[3], Cq = Cq4[3];
      float hv;
      hv = __builtin_amdgcn_fmed3f(fmaf(h[12], dtv*Av[12], xd*Bq.x), -1e6f, 1e6f); h[12] = hv; y0 = fmaf(hv, Cq.x, y0);
      hv = __builtin_amdgcn_fmed3f(fmaf(h[13], dtv*Av[13], xd*Bq.y), -1e6f, 1e6f); h[13] = hv; y1 = fmaf(hv, Cq.y, y1);
      hv = __builtin_amdgcn_fmed3f(fmaf(h[14], dtv*Av[14], xd*Bq.z), -1e6f, 1e6f); h[14] = hv; y2 = fmaf(hv, Cq.z, y2);
      hv = __builtin_amdgcn_fmed3f(fmaf(h[15], dtv*Av[15], xd*Bq.w), -1e6f, 1e6f); h[15] = hv; y3 = fmaf(hv, Cq.w, y3);
    }
    *(float4*)(hidp + (size_t)t * 1024 +  0) = make_float4(h[0],  h[1],  h[2],  h[3]);
    *(float4*)(hidp + (size_t)t * 1024 +  4) = make_float4(h[4],  h[5],  h[6],  h[7]);
    *(float4*)(hidp + (size_t)t * 1024 +  8) = make_float4(h[8],  h[9],  h[10], h[11]);
    *(float4*)(hidp + (size_t)t * 1024 + 12) = make_float4(h[12], h[13], h[14], h[15]);
    outp[(size_t)t * 64] = fmaf(Dpv, xv, (y0 + y1) + (y2 + y3));
  };
  auto comp8 = [&](float (&db)[8], float (&xb)[8], int T) {
#pragma unroll
    for (int q = 0; q < 8; ++q) step(db[q], xb[q], T + q);
  };

  comp8(dA8, xA8, 0);  load8(dA8, xA8, 16);
  comp8(dB8, xB8, 8);  load8(dB8, xB8, 24);
  comp8(dA8, xA8, 16);
  comp8(dB8, xB8, 24);
}

extern "C" void kernel_launch(void* const* d_in, const int* in_sizes, int n_in,
                              void* d_out, int out_size, void* d_ws, size_t ws_size,
                              hipStream_t stream) {
  (void)in_sizes; (void)n_in; (void)out_size; (void)ws_size;
  const float* x     = (const float*)d_in[0];
  const float* Wx    = (const float*)d_in[1];
  const float* bx    = (const float*)d_in[2];
  const float* Wdt   = (const float*)d_in[3];
  const float* bdt   = (const float*)d_in[4];
  const float* A_log = (const float*)d_in[5];
  const float* Dp    = (const float*)d_in[6];
  float* out    = (float*)d_out;
  float* hidden = out + (size_t)NB * SEQ * 64;
  float* ws     = (float*)d_ws;
  float2* Pp    = (float2*)(ws + 12582912);

  ssm_prep<<<dim3(2048), dim3(256), 0, stream>>>(x, Wx, bx, Wdt, bdt, A_log, ws, Pp);
  ssm_carry<<<dim3(128), dim3(256), 0, stream>>>(Pp);
  ssm_scan<<<dim3(4096), dim3(64), 0, stream>>>(ws, x, A_log, Dp, out, hidden);
}

// Round 10
// 228.307 us; speedup vs baseline: 1.6852x; 1.1568x over previous
//
#include <hip/hip_runtime.h>

#define SEQ    4096
#define NB     32
#define NC     128        // chunks per sequence
#define CSTEPS 32         // steps per chunk

// ws layout (floats):
//  dtD [32][4096][64]         @ 0
//  BD  [32][4096][16]         @ 8388608
//  CD  [32][4096][16]         @ 10485760
//  Pp  float2 [32][128][1024] @ 12582912  (cell = d*16+n; carry rewrites .x=Hin)
// total 20971520 floats = 83.9 MB

__device__ __forceinline__ void async_copy16(const float* g, float* l) {
  __builtin_amdgcn_global_load_lds(
      (const __attribute__((address_space(1))) void*)g,
      (__attribute__((address_space(3))) void*)l, 16, 0, 0);
}

// quad_perm DPP add (ctrl < 0x100): lane i reads lane (i&~3)|perm[i&3]
template <int CTRL>
__device__ __forceinline__ float qp_add(float s) {
  return s + __int_as_float(__builtin_amdgcn_update_dpp(
                 0, __float_as_int(s), CTRL, 0xf, 0xf, false));
}

// ------------- Phase 1: projections + per-chunk aggregates (fused) ---------
__global__ __launch_bounds__(256, 4) void ssm_prep(
    const float* __restrict__ x, const float* __restrict__ Wx,
    const float* __restrict__ bx, const float* __restrict__ Wdt,
    const float* __restrict__ bdt, const float* __restrict__ A_log,
    float* __restrict__ ws, float2* __restrict__ Pp) {
  __shared__ float dts[64 * 64];   // [t][d]
  __shared__ float xds[64 * 64];   // [t][d] = x*dt
  __shared__ float Bs[64 * 16];    // [t][n]
  const int tid = threadIdx.x;
  const int w = tid >> 6;
  const int l = tid & 63;
  const int b = blockIdx.x >> 6;
  const int t0 = (blockIdx.x & 63) << 6;

  const int lr = l < 36 ? l : 35;
  float wrow[64];
#pragma unroll
  for (int i = 0; i < 16; ++i) {
    const float4 v = ((const float4*)(Wx + lr * 64))[i];
    wrow[4 * i + 0] = v.x; wrow[4 * i + 1] = v.y;
    wrow[4 * i + 2] = v.z; wrow[4 * i + 3] = v.w;
  }
  const float bxv = bx[lr];
  const float4 wdtv = ((const float4*)Wdt)[l];
  const float bdtv = bdt[l];

  float xiv[16];
#pragma unroll
  for (int i = 0; i < 16; ++i)
    xiv[i] = x[((size_t)b * SEQ + (t0 + (w << 4) + i)) * 64 + l];

  float* dtD = ws;
  float* BD  = ws + 8388608;
  float* CD  = ws + 10485760;

#pragma unroll
  for (int i = 0; i < 16; ++i) {
    const int tl = (w << 4) + i;          // local t
    const int t  = t0 + tl;
    const int xibits = __float_as_int(xiv[i]);
    float acc0 = bxv, acc1 = 0.f;
#pragma unroll
    for (int dj = 0; dj < 64; dj += 2) {
      acc0 = fmaf(wrow[dj],     __int_as_float(__builtin_amdgcn_readlane(xibits, dj)),     acc0);
      acc1 = fmaf(wrow[dj + 1], __int_as_float(__builtin_amdgcn_readlane(xibits, dj + 1)), acc1);
    }
    const float acc = acc0 + acc1;       // xp[l], valid l<36
    const int ab = __float_as_int(acc);
    float dtv = bdtv;
    dtv = fmaf(wdtv.x, __int_as_float(__builtin_amdgcn_readlane(ab, 16)), dtv);
    dtv = fmaf(wdtv.y, __int_as_float(__builtin_amdgcn_readlane(ab, 17)), dtv);
    dtv = fmaf(wdtv.z, __int_as_float(__builtin_amdgcn_readlane(ab, 18)), dtv);
    dtv = fmaf(wdtv.w, __int_as_float(__builtin_amdgcn_readlane(ab, 19)), dtv);
    dtD[((size_t)b * SEQ + t) * 64 + l] = dtv;
    dts[tl * 64 + l] = dtv;
    xds[tl * 64 + l] = xiv[i] * dtv;
    if (l < 16) {
      BD[((size_t)b * SEQ + t) * 16 + l] = acc;
      Bs[tl * 16 + l] = acc;
    } else if (l >= 20 && l < 36) {
      CD[((size_t)b * SEQ + t) * 16 + (l - 20)] = acc;
    }
  }
  __syncthreads();

  // Phase B: per-chunk aggregates. thread -> d = tid>>2, n = n0..n0+3
  const int d  = tid >> 2;
  const int n0 = (tid & 3) << 2;
  float Av4[4];
  {
    const float4 a = *(const float4*)(A_log + d * 16 + n0);
    Av4[0] = -expf(a.x); Av4[1] = -expf(a.y);
    Av4[2] = -expf(a.z); Av4[3] = -expf(a.w);
  }
  float2* PpB = Pp + (size_t)b * (128 * 1024);
#pragma unroll
  for (int cl = 0; cl < 2; ++cl) {
    float P0 = 1.f, P1 = 1.f, P2 = 1.f, P3 = 1.f;
    float q0 = 0.f, q1 = 0.f, q2 = 0.f, q3 = 0.f;
#pragma unroll
    for (int s = 0; s < 32; ++s) {
      const int tl = (cl << 5) + s;
      const float dtv = dts[tl * 64 + d];
      const float xdt = xds[tl * 64 + d];
      const float4 Bq = *(const float4*)(&Bs[tl * 16 + n0]);
      float dA;
      dA = dtv * Av4[0]; q0 = fmaf(q0, dA, xdt * Bq.x); P0 *= dA;
      dA = dtv * Av4[1]; q1 = fmaf(q1, dA, xdt * Bq.y); P1 *= dA;
      dA = dtv * Av4[2]; q2 = fmaf(q2, dA, xdt * Bq.z); P2 *= dA;
      dA = dtv * Av4[3]; q3 = fmaf(q3, dA, xdt * Bq.w); P3 *= dA;
    }
    const int c = (t0 >> 5) + cl;
    float4* dst = (float4*)(PpB + (size_t)c * 1024 + d * 16 + n0);
    dst[0] = make_float4(P0, q0, P1, q1);
    dst[1] = make_float4(P2, q2, P3, q3);
  }
}

// ------------- Phase 2: serial carry, batched prefetch; Hin -> Pp[.].x -----
__global__ __launch_bounds__(256) void ssm_carry(float2* __restrict__ Pp) {
  const int b = blockIdx.x >> 2;
  const int cell = ((blockIdx.x & 3) << 8) + threadIdx.x;
  float2* base = Pp + (size_t)b * (128 * 1024) + cell;
  float H = 0.f;
#pragma unroll
  for (int g = 0; g < 8; ++g) {
    float2 v[16];
#pragma unroll
    for (int j = 0; j < 16; ++j) v[j] = base[(size_t)(g * 16 + j) * 1024];
#pragma unroll
    for (int j = 0; j < 16; ++j) {
      base[(size_t)(g * 16 + j) * 1024].x = H;
      H = fmaf(v[j].x, H, v[j].y);
    }
  }
}

// ------------- Phase 3: scan; lane = (d_local, n-quad); h[4]/lane ----------
__global__ __launch_bounds__(64, 6) void ssm_scan(
    const float* __restrict__ ws, const float* __restrict__ x,
    const float* __restrict__ A_log, const float* __restrict__ Dp,
    float* __restrict__ out, float* __restrict__ hidden) {
  __shared__ __align__(16) float Bs[512];
  __shared__ __align__(16) float Cs[512];
  const int lane = threadIdx.x;
  const int id = blockIdx.x;             // ((b*128 + c)*4 + dq)
  const int dq = id & 3;
  const int c  = (id >> 2) & 127;
  const int b  = id >> 9;
  const int t0 = c << 5;
  const int dl = lane >> 2;              // d within quarter
  const int nq = lane & 3;               // n-quad
  const int d  = (dq << 4) + dl;

  const float* Bg = ws + 8388608  + ((size_t)b * SEQ + t0) * 16;
  const float* Cg = ws + 10485760 + ((size_t)b * SEQ + t0) * 16;
  async_copy16(Bg + lane * 4, Bs);
  async_copy16(Bg + 256 + lane * 4, Bs + 256);
  async_copy16(Cg + lane * 4, Cs);
  async_copy16(Cg + 256 + lane * 4, Cs + 256);

  const float* dtp = ws + ((size_t)b * SEQ + t0) * 64 + d;
  const float* xpp = x  + ((size_t)b * SEQ + t0) * 64 + d;

  float dA8[8], xA8[8], dB8[8], xB8[8];
  auto load8 = [&](float (&db)[8], float (&xb)[8], int T) {
#pragma unroll
    for (int j = 0; j < 8; ++j) {
      db[j] = dtp[(size_t)(T + j) * 64];
      xb[j] = xpp[(size_t)(T + j) * 64];
    }
  };
  load8(dA8, xA8, 0);
  load8(dB8, xB8, 8);

  float Av[4];
  {
    const float4 a = *(const float4*)(A_log + d * 16 + (nq << 2));
    Av[0] = -expf(a.x); Av[1] = -expf(a.y);
    Av[2] = -expf(a.z); Av[3] = -expf(a.w);
  }
  const float Dpv = Dp[d];

  float h[4];
  {
    const float4* pp = (const float4*)(ws + 12582912 +
        ((size_t)(b * 128 + c) * 1024 + d * 16 + (nq << 2)) * 2);
    const float4 v0 = pp[0], v1 = pp[1];
    h[0] = v0.x; h[1] = v0.z; h[2] = v1.x; h[3] = v1.z;  // .x = Hin
  }

  // hidden[b][t][d][n]: lane writes 16B at byte offset 16*lane within the
  // chunk-quarter slab -> contiguous 1KB per wave store instruction.
  float* hidp = hidden + ((size_t)b * SEQ + t0) * 1024 + (dq << 8) + (lane << 2);
  float* outp = out + ((size_t)b * SEQ + t0) * 64 + d;

  asm volatile("s_waitcnt vmcnt(0)" ::: "memory");

  auto step = [&](float dtv, float xv, int t) {
    const float xd = xv * dtv;
    const float4 Bq = *(const float4*)(Bs + t * 16 + (nq << 2));
    const float4 Cq = *(const float4*)(Cs + t * 16 + (nq << 2));
    float y;
    float hv;
    hv = __builtin_amdgcn_fmed3f(fmaf(h[0], dtv * Av[0], xd * Bq.x), -1e6f, 1e6f);
    h[0] = hv; y = hv * Cq.x;
    hv = __builtin_amdgcn_fmed3f(fmaf(h[1], dtv * Av[1], xd * Bq.y), -1e6f, 1e6f);
    h[1] = hv; y = fmaf(hv, Cq.y, y);
    hv = __builtin_amdgcn_fmed3f(fmaf(h[2], dtv * Av[2], xd * Bq.z), -1e6f, 1e6f);
    h[2] = hv; y = fmaf(hv, Cq.z, y);
    hv = __builtin_amdgcn_fmed3f(fmaf(h[3], dtv * Av[3], xd * Bq.w), -1e6f, 1e6f);
    h[3] = hv; y = fmaf(hv, Cq.w, y);
    *(float4*)(hidp + (size_t)t * 1024) = make_float4(h[0], h[1], h[2], h[3]);
    y = qp_add<0xB1>(y);   // quad_perm [1,0,3,2]
    y = qp_add<0x4E>(y);   // quad_perm [2,3,0,1] -> full quad sum
    if (nq == 0) outp[(size_t)t * 64] = fmaf(Dpv, xv, y);
  };
  auto comp8 = [&](float (&db)[8], float (&xb)[8], int T) {
#pragma unroll
    for (int q = 0; q < 8; ++q) step(db[q], xb[q], T + q);
  };

  comp8(dA8, xA8, 0);  load8(dA8, xA8, 16);
  comp8(dB8, xB8, 8);  load8(dB8, xB8, 24);
  comp8(dA8, xA8, 16);
  comp8(dB8, xB8, 24);
}

extern "C" void kernel_launch(void* const* d_in, const int* in_sizes, int n_in,
                              void* d_out, int out_size, void* d_ws, size_t ws_size,
                              hipStream_t stream) {
  (void)in_sizes; (void)n_in; (void)out_size; (void)ws_size;
  const float* x     = (const float*)d_in[0];
  const float* Wx    = (const float*)d_in[1];
  const float* bx    = (const float*)d_in[2];
  const float* Wdt   = (const float*)d_in[3];
  const float* bdt   = (const float*)d_in[4];
  const float* A_log = (const float*)d_in[5];
  const float* Dp    = (const float*)d_in[6];
  float* out    = (float*)d_out;
  float* hidden = out + (size_t)NB * SEQ * 64;
  float* ws     = (float*)d_ws;
  float2* Pp    = (float2*)(ws + 12582912);

  ssm_prep<<<dim3(2048), dim3(256), 0, stream>>>(x, Wx, bx, Wdt, bdt, A_log, ws, Pp);
  ssm_carry<<<dim3(128), dim3(256), 0, stream>>>(Pp);
  ssm_scan<<<dim3(16384), dim3(64), 0, stream>>>(ws, x, A_log, Dp, out, hidden);
}